// Round 16
// baseline (269.365 us; speedup 1.0000x reference)
//
#include <hip/hip_runtime.h>

// ---------------------------------------------------------------------------
// SAGAN self-attention block, MI355X / gfx950.
// B=4, C=256, H=W=64 (HW=4096), Ck=32.
// v20: register-resident P.  QK reads Qt with permuted A-rows
// (rho = half*32 + (l15>>2)*8 + mi2*4 + (l15&3)) so each lane's QK output
// is already in PV A-fragment order (n=l15 rows, k=quad*8+mi2*4+r).  PV
// re-split: wave owns (16n x its 32m) of P vs ALL 256 channels -> 16 MFMAs
// from registers, no P LDS exchange (was 8KB wr + 64KB rd per block-iter).
// O[16] f32x4 partial per wave; 4 key/half partials merged in k_merge<4>.
// V stored m-block-major by k_proj so PV's 16 loads stream one base.
// LDS = Qt[2]+lsum (~16.6 KB).  k_prep = v17, k_proj = v16 + V relayout.
// ---------------------------------------------------------------------------

constexpr int kC   = 256;
constexpr int kHW  = 4096;
constexpr int kB   = 4;
constexpr int kCHW = kC * kHW;

typedef short bf16x8 __attribute__((ext_vector_type(8)));
typedef float f32x4  __attribute__((ext_vector_type(4)));
typedef unsigned short u16;

#if __has_builtin(__builtin_amdgcn_exp2f)
#define EXP2(x) __builtin_amdgcn_exp2f(x)
#else
#define EXP2(x) exp2f(x)
#endif

__device__ __forceinline__ u16 f2bf(float f) {
    union { float f; unsigned u; } v; v.f = f;
    unsigned u = v.u;
    return (u16)((u + 0x7fffu + ((u >> 16) & 1u)) >> 16);  // RNE
}
__device__ __forceinline__ float bf2f(u16 h) {
    union { unsigned u; float f; } v; v.u = ((unsigned)h) << 16;
    return v.f;
}

// ---------------------------------------------------------------------------
// Kernel 1: fused prep.  Blocks 0..2: inverse spectral norms (sigma).
// Blocks 3..82: W -> bf16 hi/lo A-fragment pack (one elem per thread).
// ---------------------------------------------------------------------------
__global__ __launch_bounds__(1024) void k_prep(
    const float* __restrict__ fw, const float* __restrict__ fu,
    const float* __restrict__ gw, const float* __restrict__ gu,
    const float* __restrict__ hww, const float* __restrict__ hu,
    float* __restrict__ sig, u16* __restrict__ wh, u16* __restrict__ wl)
{
    if (blockIdx.x >= 3) {
        const int tid = (blockIdx.x - 3) * 1024 + threadIdx.x;   // 0..81919
        const int g  = tid >> 8;                                  // row 0..319
        const int ci = tid & 255;
        const float f = (g < 32) ? fw[g * 256 + ci]
                      : (g < 64) ? gw[(g - 32) * 256 + ci]
                                 : hww[(g - 64) * 256 + ci];
        const int idx = ((g >> 4) * 8 + (ci >> 5)) * 512 + (g & 15) * 32 + (ci & 31);
        const u16 h = f2bf(f);
        wh[idx] = h;
        wl[idx] = f2bf(f - bf2f(h));
        return;
    }

    const int which = blockIdx.x;
    const float* W = which == 0 ? fw : (which == 1 ? gw : hww);
    const float* U = which == 0 ? fu : (which == 1 ? gu : hu);
    const int O = (which == 2) ? 256 : 32;
    const int t = threadIdx.x;

    __shared__ float par[4][256];
    __shared__ float red[256];
    __shared__ __align__(16) float Vv[256];

    {
        const int i = t & 255, och = t >> 8;
        float p = 0.f;
        if (O == 256) {
            const float* Wc = W + (size_t)(och * 64) * 256 + i;
            const float* Uc = U + och * 64;
#pragma unroll 8
            for (int oo = 0; oo < 64; ++oo)
                p += Uc[oo] * Wc[(size_t)oo * 256];
        } else if (och == 0) {
            const float* Wc = W + i;
#pragma unroll 8
            for (int oo = 0; oo < 32; ++oo)
                p += U[oo] * Wc[(size_t)oo * 256];
        }
        par[och][i] = p;
    }
    __syncthreads();
    float t1 = 0.f;
    if (t < 256) {
        t1 = par[0][t] + par[1][t] + par[2][t] + par[3][t];
        red[t] = t1 * t1;
    }
    __syncthreads();
    for (int s = 128; s > 0; s >>= 1) { if (t < s) red[t] += red[t + s]; __syncthreads(); }
    if (t < 256) Vv[t] = t1 / fmaxf(sqrtf(red[0]), 1e-12f);
    __syncthreads();

    {
        const int o = t & 255, ich = t >> 8;
        float q = 0.f;
        if (o < O) {
            const float4* Wr = (const float4*)(W + (size_t)o * 256 + ich * 64);
            const float4* Vr = (const float4*)(&Vv[ich * 64]);
#pragma unroll
            for (int j = 0; j < 16; ++j) {
                const float4 w = Wr[j]; const float4 v = Vr[j];
                q += w.x * v.x + w.y * v.y + w.z * v.z + w.w * v.w;
            }
        }
        par[ich][o] = q;
    }
    __syncthreads();
    if (t < 256) {
        const float t2 = par[0][t] + par[1][t] + par[2][t] + par[3][t];
        red[t] = t2 * t2;
    }
    __syncthreads();
    for (int s = 128; s > 0; s >>= 1) { if (t < s) red[t] += red[t + s]; __syncthreads(); }
    if (t == 0) {
        const float s2 = red[0];
        sig[which] = fmaxf(sqrtf(s2), 1e-12f) / s2;   // 1/sigma
    }
}

// ---------------------------------------------------------------------------
// Kernel 2: all projections as one MFMA GEMM.  grid (64 n-tiles, 4 b),
// 512 thr (8 waves).  K/Q epilogue stores vectorized (uint2 hi + uint2 lo).
// Q-path sigma & bias pre-scaled by log2(e).
// V stored m-block-major: idx = ((m>>5)*256 + c)*32 + (m&31)  per batch.
// ---------------------------------------------------------------------------
__global__ __launch_bounds__(512) void k_proj(
    const float* __restrict__ x,
    const u16* __restrict__ wh, const u16* __restrict__ wl,
    const float* __restrict__ fb, const float* __restrict__ gb,
    const float* __restrict__ hb, const float* __restrict__ sig,
    u16* __restrict__ Kc, u16* __restrict__ Qc, u16* __restrict__ Vb)
{
    __shared__ __align__(16) float xs[256][64];  // 64 KB
    __shared__ float bLDS[320];

    const int t = threadIdx.x;
    const int wave = t >> 6, lane = t & 63;
    const int quad = lane >> 4, l15 = lane & 15;
    const int b = blockIdx.y;
    const int n0 = blockIdx.x * 64;
    const int nch = wave & 3, cohalf = wave >> 2;

    constexpr float kLog2e = 1.44269504f;

    // stage x tile [256 ci][64 n]
    {
        const int r4i = lane >> 4, c16 = lane & 15;
        const float* xg = x + (size_t)b * kCHW + (size_t)r4i * kHW + n0 + c16 * 4;
#pragma unroll
        for (int j = 0; j < 8; ++j) {
            const int cibase = (wave * 8 + j) * 4;
            __builtin_amdgcn_global_load_lds(
                (const __attribute__((address_space(1))) void*)(xg + (size_t)cibase * kHW),
                (__attribute__((address_space(3))) void*)&xs[cibase][0], 16, 0, 0);
        }
    }
    if (t < 320) bLDS[t] = (t < 32) ? fb[t]
                         : (t < 64) ? gb[t - 32] * kLog2e
                         : hb[t - 64];
    __syncthreads();

    // B-frags (x) hi/lo for 8 ci-slices; lane = col n
    const int n = nch * 16 + l15;
    bf16x8 bh[8], bl[8];
#pragma unroll
    for (int s = 0; s < 8; ++s) {
        union { u16 a[8]; bf16x8 v; } H, L;
#pragma unroll
        for (int j = 0; j < 8; ++j) {
            const float v = xs[s * 32 + quad * 8 + j][n];
            const u16 h = f2bf(v);
            H.a[j] = h; L.a[j] = f2bf(v - bf2f(h));
        }
        bh[s] = H.v; bl[s] = L.v;
    }

    // A-frag lane base into packed layout
    const u16* whp = wh + l15 * 32 + quad * 8;
    const u16* wlp = wl + l15 * 32 + quad * 8;

    f32x4 acc[10] = {};
#pragma unroll
    for (int c = 0; c < 10; ++c) {
        const size_t base = (size_t)(cohalf * 10 + c) * 4096;
#pragma unroll
        for (int s = 0; s < 8; ++s) {
            const bf16x8 ah = *(const bf16x8*)(whp + base + s * 512);
            const bf16x8 al = *(const bf16x8*)(wlp + base + s * 512);
            acc[c] = __builtin_amdgcn_mfma_f32_16x16x32_bf16(ah, bh[s], acc[c], 0, 0, 0);
            acc[c] = __builtin_amdgcn_mfma_f32_16x16x32_bf16(ah, bl[s], acc[c], 0, 0, 0);
            acc[c] = __builtin_amdgcn_mfma_f32_16x16x32_bf16(al, bh[s], acc[c], 0, 0, 0);
        }
    }

    const float s0 = sig[0], s1 = sig[1] * kLog2e, s2 = sig[2];
    const int m = n0 + n;
    const size_t vmbase = (size_t)b * kC * kHW + ((size_t)(m >> 5) * 256) * 32 + (m & 31);
#pragma unroll
    for (int c = 0; c < 10; ++c) {
        const int cog0 = (cohalf * 10 + c) * 16;
        const float inv = (cog0 < 32) ? s0 : (cog0 < 64) ? s1 : s2;
        if (cog0 < 64) {
            // K/Q: r=0..3 -> consecutive d; pack into uint2 hi + uint2 lo
            u16 hi[4], lo[4];
#pragma unroll
            for (int r = 0; r < 4; ++r) {
                const float v = acc[c][r] * inv + bLDS[cog0 + quad * 4 + r];
                hi[r] = f2bf(v);
                lo[r] = f2bf(v - bf2f(hi[r]));
            }
            u16* H = (cog0 < 32) ? Kc : Qc;
            const int dbase = (cog0 & 31) + quad * 4;
            const size_t off = (size_t)(b * kHW + m) * 64;
            const unsigned h01 = (unsigned)hi[0] | ((unsigned)hi[1] << 16);
            const unsigned h23 = (unsigned)hi[2] | ((unsigned)hi[3] << 16);
            const unsigned l01 = (unsigned)lo[0] | ((unsigned)lo[1] << 16);
            const unsigned l23 = (unsigned)lo[2] | ((unsigned)lo[3] << 16);
            *(uint2*)(H + off + dbase)      = make_uint2(h01, h23);
            *(uint2*)(H + off + 32 + dbase) = make_uint2(l01, l23);
        } else {
#pragma unroll
            for (int r = 0; r < 4; ++r) {
                const int co = cog0 + quad * 4 + r;
                const float v = acc[c][r] * inv + bLDS[co];
                Vb[vmbase + (size_t)(co - 64) * 32] = f2bf(v);
            }
        }
    }
}

// ---------------------------------------------------------------------------
// Kernel 3: flash attention v20, register-resident P.  grid 512
// (XCD-swizzled; id>>8 = key-half), 512 thr (8 waves).  Per iter:
// {stage Qt_{i+1}; QK_i with permuted A-rows; exp2 -> pa (regs); PV_i:
// 16 MFMAs vs all 256 channels from V (m-block-major, L2); BAR}.
// No P LDS.  Wave (sg,half) writes partial p = mh*2+half of O.
// ---------------------------------------------------------------------------
__global__ __launch_bounds__(512, 4) void k_attn(
    const u16* __restrict__ Kc, const u16* __restrict__ Qc,
    const u16* __restrict__ Vb,
    u16* __restrict__ Op, float* __restrict__ Sl)
{
    __shared__ __align__(16) u16 Qt[2][4096];   // 16 KB
    __shared__ float lsum[8][16];

    const int t = threadIdx.x;
    const int wave = t >> 6, lane = t & 63;
    const int quad = lane >> 4, l15 = lane & 15;
    const int sg = wave >> 1, half = wave & 1;

    const int id = blockIdx.x;
    const int xcd = id & 7;
    const int b = xcd >> 1;
    const int nb0 = ((xcd & 1) * 32 + ((id >> 3) & 31)) * 64;
    const int mh = id >> 8;                    // key-half
    const int mt0 = mh * 32, mt1 = mt0 + 32;

    const u16* Kb  = Kc + (size_t)b * kHW * 64;
    const u16* Qb  = Qc + (size_t)b * kHW * 64;
    const u16* Vbb = Vb + (size_t)b * kC * kHW;   // m-block-major

    const size_t krow = (size_t)(nb0 + sg * 16 + l15) * 64 + (size_t)quad * 8;
    const bf16x8 kh = *(const bf16x8*)(Kb + krow);
    const bf16x8 kl = *(const bf16x8*)(Kb + krow + 32);

    const int qs_row = lane >> 3, qs_ch = lane & 7;
    const int rloc = wave * 8 + qs_row;
    const int qswz = (qs_ch ^ (rloc & 7)) << 3;

    // permuted Qt read row (mi2=0); mi2 adds +4.  rho in [half*32, half*32+32)
    const int rho0 = half * 32 + ((l15 >> 2) << 3) + (l15 & 3);

    f32x4 O[16] = {};
    float lrow = 0.f;

    // ---- prologue: stage Qt[0] (tile mt0), barrier ----
    __builtin_amdgcn_global_load_lds(
        (const __attribute__((address_space(1))) void*)
            (Qb + (size_t)(mt0 * 64 + rloc) * 64 + qswz),
        (__attribute__((address_space(3))) void*)&Qt[0][wave * 512], 16, 0, 0);
    __syncthreads();

    for (int mt = mt0; mt < mt1; ++mt) {
        const int cur = mt & 1;
        const int m0 = mt * 64;   // key units

        // ---- issue Qt load for tile mt+1 (consumed after next barrier) ----
        if (mt < mt1 - 1) {
            __builtin_amdgcn_global_load_lds(
                (const __attribute__((address_space(1))) void*)
                    (Qb + (size_t)(m0 + 64 + rloc) * 64 + qswz),
                (__attribute__((address_space(3))) void*)&Qt[cur ^ 1][wave * 512], 16, 0, 0);
        }

        // ---- QK with permuted A-rows (Qt[cur] ready since c_{i-1}) ----
        f32x4 s[2];
        __builtin_amdgcn_s_setprio(1);
#pragma unroll
        for (int mi2 = 0; mi2 < 2; ++mi2) {
            const int rho = rho0 + mi2 * 4;
            const int rsw = rho & 7;
            const bf16x8 qhv = *(const bf16x8*)&Qt[cur][rho * 64 + ((quad       ^ rsw) << 3)];
            const bf16x8 qlv = *(const bf16x8*)&Qt[cur][rho * 64 + (((quad + 4) ^ rsw) << 3)];
            f32x4 a = { 0.f, 0.f, 0.f, 0.f };
            a = __builtin_amdgcn_mfma_f32_16x16x32_bf16(qhv, kl, a, 0, 0, 0);
            a = __builtin_amdgcn_mfma_f32_16x16x32_bf16(qlv, kh, a, 0, 0, 0);
            a = __builtin_amdgcn_mfma_f32_16x16x32_bf16(qhv, kh, a, 0, 0, 0);
            s[mi2] = a;
        }
        __builtin_amdgcn_s_setprio(0);

        // ---- exp2 + l accumulate + pack PV A-fragment in registers ----
        union { unsigned u[4]; bf16x8 v; } PA;
        {
            const float e00 = EXP2(s[0][0]), e01 = EXP2(s[0][1]);
            const float e02 = EXP2(s[0][2]), e03 = EXP2(s[0][3]);
            const float e10 = EXP2(s[1][0]), e11 = EXP2(s[1][1]);
            const float e12 = EXP2(s[1][2]), e13 = EXP2(s[1][3]);
            lrow += ((e00 + e01) + (e02 + e03)) + ((e10 + e11) + (e12 + e13));
            PA.u[0] = __builtin_amdgcn_perm(__float_as_uint(e01), __float_as_uint(e00), 0x07060302u);
            PA.u[1] = __builtin_amdgcn_perm(__float_as_uint(e03), __float_as_uint(e02), 0x07060302u);
            PA.u[2] = __builtin_amdgcn_perm(__float_as_uint(e11), __float_as_uint(e10), 0x07060302u);
            PA.u[3] = __builtin_amdgcn_perm(__float_as_uint(e13), __float_as_uint(e12), 0x07060302u);
        }

        // ---- PV: 16 MFMAs vs all channels; V from L2 (m-block-major) ----
        {
            const u16* vb = Vbb + (size_t)(mt * 2 + half) * 8192 + l15 * 32 + quad * 8;
            __builtin_amdgcn_s_setprio(1);
#pragma unroll
            for (int ct = 0; ct < 16; ++ct) {
                const bf16x8 vv = *(const bf16x8*)(vb + ct * 512);
                O[ct] = __builtin_amdgcn_mfma_f32_16x16x32_bf16(PA.v, vv, O[ct], 0, 0, 0);
            }
            __builtin_amdgcn_s_setprio(0);
        }

        __syncthreads();   // single barrier: Qt[cur^1] staged for next iter
    }

    // ---- epilogue: reduce l once, write bf16 partial O + l ----
    lrow += __shfl_xor(lrow, 16);
    lrow += __shfl_xor(lrow, 32);
    if (lane < 16) lsum[wave][l15] = lrow;
    __syncthreads();
    if (half == 0 && lane < 16)
        Sl[(size_t)(mh * 4 + b) * kHW + nb0 + sg * 16 + l15]
            = lsum[wave][l15] + lsum[wave ^ 1][l15];

    u16* Opb = Op + ((size_t)(mh * 2 + half) * 4 + b) * (size_t)kHW * 256;
#pragma unroll
    for (int ct = 0; ct < 16; ++ct) {
#pragma unroll
        for (int r = 0; r < 4; ++r) {
            const int nn = nb0 + sg * 16 + quad * 4 + r;
            const int c = ct * 16 + l15;
            Opb[(size_t)nn * 256 + c] = f2bf(O[ct][r]);
        }
    }
}

// ---------------------------------------------------------------------------
// Kernel 4: merge NS O-partials + epilogue.  grid 2048 x 256 thr,
// 8 channels per thread, fully coalesced.  Max-free partials: plain sums.
// l = sum of the two key-half sums in Sl.
// ---------------------------------------------------------------------------
template <int NS>
__global__ __launch_bounds__(256) void k_merge(
    const float* __restrict__ x, const float* __restrict__ gamma,
    const u16* __restrict__ Op, const float* __restrict__ Sl,
    float* __restrict__ out)
{
    const int tid = blockIdx.x * 256 + threadIdx.x;
    const int cg = tid & 31;
    const int n  = (tid >> 5) & 4095;
    const int b  = tid >> 17;
    const int c0 = cg * 8;

    const float la = Sl[(size_t)b * kHW + n];
    const float lb = Sl[(size_t)(4 + b) * kHW + n];
    const float invL = 1.f / (la + lb);
    const float g = gamma[0];

    const size_t base = ((size_t)b * kHW + n) * 256 + c0;

    float o[8] = {};
#pragma unroll
    for (int s = 0; s < NS; ++s) {
        const uint4 A = *(const uint4*)(Op + base + (size_t)s * 4 * kHW * 256);
        const unsigned aw[4] = { A.x, A.y, A.z, A.w };
#pragma unroll
        for (int j = 0; j < 8; ++j)
            o[j] += bf2f((u16)(aw[j >> 1] >> ((j & 1) * 16)));
    }

    const float4 x0 = *(const float4*)(x + base);
    const float4 x1 = *(const float4*)(x + base + 4);
    float4 r0, r1;
    r0.x = g * o[0] * invL + x0.x; r0.y = g * o[1] * invL + x0.y;
    r0.z = g * o[2] * invL + x0.z; r0.w = g * o[3] * invL + x0.w;
    r1.x = g * o[4] * invL + x1.x; r1.y = g * o[5] * invL + x1.y;
    r1.z = g * o[6] * invL + x1.z; r1.w = g * o[7] * invL + x1.w;
    *(float4*)(out + base)     = r0;
    *(float4*)(out + base + 4) = r1;
}

// ---------------------------------------------------------------------------
extern "C" void kernel_launch(void* const* d_in, const int* in_sizes, int n_in,
                              void* d_out, int out_size, void* d_ws, size_t ws_size,
                              hipStream_t stream)
{
    const float* x     = (const float*)d_in[0];
    const float* fw    = (const float*)d_in[1];
    const float* fb    = (const float*)d_in[2];
    const float* fu    = (const float*)d_in[3];
    const float* gw    = (const float*)d_in[4];
    const float* gb    = (const float*)d_in[5];
    const float* gu    = (const float*)d_in[6];
    const float* hww   = (const float*)d_in[7];
    const float* hb    = (const float*)d_in[8];
    const float* hu    = (const float*)d_in[9];
    const float* gamma = (const float*)d_in[10];
    float* out = (float*)d_out;

    // Compact layout (<= 45.4 MB, proven to fit by v10's ns=4 run):
    //   sig@0 | wh@1KB (160KB) | wl (160KB) | Kc@512KB (2MB) | Qc@2.5MB (2MB)
    //   Vb@4.5MB (8MB) | Op@12.5MB (32MB: 4 partials) | Sl@44.5MB (128KB)
    char* ws = (char*)d_ws;
    float* sig = (float*)ws;
    u16* wh = (u16*)(ws + 1024);
    u16* wl = wh + 320 * 256;
    u16* Kc = (u16*)(ws + (512u << 10));
    u16* Qc = (u16*)(ws + (2560u << 10));
    u16* Vb = (u16*)(ws + (4608u << 10));
    u16* Op = (u16*)(ws + (12800u << 10));
    float* Sl = (float*)(ws + (12800u << 10) + 4ull * 8 * 1024 * 1024);

    k_prep<<<dim3(83), dim3(1024), 0, stream>>>(fw, fu, gw, gu, hww, hu, sig, wh, wl);
    k_proj<<<dim3(64, 4), dim3(512), 0, stream>>>(x, wh, wl, fb, gb, hb, sig,
                                                  Kc, Qc, Vb);
    k_attn<<<dim3(512), dim3(512), 0, stream>>>(Kc, Qc, Vb, Op, Sl);
    k_merge<4><<<dim3(2048), dim3(256), 0, stream>>>(x, gamma, Op, Sl, out);
}

// Round 17
// 215.931 us; speedup vs baseline: 1.2475x; 1.2475x over previous
//
#include <hip/hip_runtime.h>

// ---------------------------------------------------------------------------
// SAGAN self-attention block, MI355X / gfx950.
// B=4, C=256, H=W=64 (HW=4096), Ck=32.
// v21 = v19 (measured best, 216.46 us).  v13's k_attn verbatim -- six
// structural rewrites (v14 Q-direct, v15 Q-reg, v17 deferred-PV, v18
// paired-tiles, v20 reg-P) all regressed; its P-in-LDS / V-in-reg split is
// on the right side of the LDS(69TB/s) vs L2(34.5TB/s) amplification
// tradeoff.  + fused k_prep (sigma+pack), vectorized k_proj stores,
// coalesced k_merge.
// ---------------------------------------------------------------------------

constexpr int kC   = 256;
constexpr int kHW  = 4096;
constexpr int kB   = 4;
constexpr int kCHW = kC * kHW;

typedef short bf16x8 __attribute__((ext_vector_type(8)));
typedef float f32x4  __attribute__((ext_vector_type(4)));
typedef unsigned short u16;

#if __has_builtin(__builtin_amdgcn_exp2f)
#define EXP2(x) __builtin_amdgcn_exp2f(x)
#else
#define EXP2(x) exp2f(x)
#endif

__device__ __forceinline__ u16 f2bf(float f) {
    union { float f; unsigned u; } v; v.f = f;
    unsigned u = v.u;
    return (u16)((u + 0x7fffu + ((u >> 16) & 1u)) >> 16);  // RNE
}
__device__ __forceinline__ float bf2f(u16 h) {
    union { unsigned u; float f; } v; v.u = ((unsigned)h) << 16;
    return v.f;
}

// ---------------------------------------------------------------------------
// Kernel 1: fused prep.  Blocks 0..2: inverse spectral norms (sigma).
// Blocks 3..82: W -> bf16 hi/lo A-fragment pack (one elem per thread).
// idx = R*4096 + s*512 + l15*32 + k (R=g>>4, l15=g&15, s=ci>>5, k=ci&31);
// rows [0,32)=fw, [32,64)=gw, [64,320)=hww.
// ---------------------------------------------------------------------------
__global__ __launch_bounds__(1024) void k_prep(
    const float* __restrict__ fw, const float* __restrict__ fu,
    const float* __restrict__ gw, const float* __restrict__ gu,
    const float* __restrict__ hww, const float* __restrict__ hu,
    float* __restrict__ sig, u16* __restrict__ wh, u16* __restrict__ wl)
{
    if (blockIdx.x >= 3) {
        const int tid = (blockIdx.x - 3) * 1024 + threadIdx.x;   // 0..81919
        const int g  = tid >> 8;                                  // row 0..319
        const int ci = tid & 255;
        const float f = (g < 32) ? fw[g * 256 + ci]
                      : (g < 64) ? gw[(g - 32) * 256 + ci]
                                 : hww[(g - 64) * 256 + ci];
        const int idx = ((g >> 4) * 8 + (ci >> 5)) * 512 + (g & 15) * 32 + (ci & 31);
        const u16 h = f2bf(f);
        wh[idx] = h;
        wl[idx] = f2bf(f - bf2f(h));
        return;
    }

    const int which = blockIdx.x;
    const float* W = which == 0 ? fw : (which == 1 ? gw : hww);
    const float* U = which == 0 ? fu : (which == 1 ? gu : hu);
    const int O = (which == 2) ? 256 : 32;
    const int t = threadIdx.x;

    __shared__ float par[4][256];
    __shared__ float red[256];
    __shared__ __align__(16) float Vv[256];

    {
        const int i = t & 255, och = t >> 8;
        float p = 0.f;
        if (O == 256) {
            const float* Wc = W + (size_t)(och * 64) * 256 + i;
            const float* Uc = U + och * 64;
#pragma unroll 8
            for (int oo = 0; oo < 64; ++oo)
                p += Uc[oo] * Wc[(size_t)oo * 256];
        } else if (och == 0) {
            const float* Wc = W + i;
#pragma unroll 8
            for (int oo = 0; oo < 32; ++oo)
                p += U[oo] * Wc[(size_t)oo * 256];
        }
        par[och][i] = p;
    }
    __syncthreads();
    float t1 = 0.f;
    if (t < 256) {
        t1 = par[0][t] + par[1][t] + par[2][t] + par[3][t];
        red[t] = t1 * t1;
    }
    __syncthreads();
    for (int s = 128; s > 0; s >>= 1) { if (t < s) red[t] += red[t + s]; __syncthreads(); }
    if (t < 256) Vv[t] = t1 / fmaxf(sqrtf(red[0]), 1e-12f);
    __syncthreads();

    {
        const int o = t & 255, ich = t >> 8;
        float q = 0.f;
        if (o < O) {
            const float4* Wr = (const float4*)(W + (size_t)o * 256 + ich * 64);
            const float4* Vr = (const float4*)(&Vv[ich * 64]);
#pragma unroll
            for (int j = 0; j < 16; ++j) {
                const float4 w = Wr[j]; const float4 v = Vr[j];
                q += w.x * v.x + w.y * v.y + w.z * v.z + w.w * v.w;
            }
        }
        par[ich][o] = q;
    }
    __syncthreads();
    if (t < 256) {
        const float t2 = par[0][t] + par[1][t] + par[2][t] + par[3][t];
        red[t] = t2 * t2;
    }
    __syncthreads();
    for (int s = 128; s > 0; s >>= 1) { if (t < s) red[t] += red[t + s]; __syncthreads(); }
    if (t == 0) {
        const float s2 = red[0];
        sig[which] = fmaxf(sqrtf(s2), 1e-12f) / s2;   // 1/sigma
    }
}

// ---------------------------------------------------------------------------
// Kernel 2: all projections as one MFMA GEMM.  grid (64 n-tiles, 4 b),
// 512 thr (8 waves).  K/Q epilogue stores vectorized (uint2 hi + uint2 lo).
// Q-path sigma & bias pre-scaled by log2(e).
// ---------------------------------------------------------------------------
__global__ __launch_bounds__(512) void k_proj(
    const float* __restrict__ x,
    const u16* __restrict__ wh, const u16* __restrict__ wl,
    const float* __restrict__ fb, const float* __restrict__ gb,
    const float* __restrict__ hb, const float* __restrict__ sig,
    u16* __restrict__ Kc, u16* __restrict__ Qc, u16* __restrict__ Vb)
{
    __shared__ __align__(16) float xs[256][64];  // 64 KB
    __shared__ float bLDS[320];

    const int t = threadIdx.x;
    const int wave = t >> 6, lane = t & 63;
    const int quad = lane >> 4, l15 = lane & 15;
    const int b = blockIdx.y;
    const int n0 = blockIdx.x * 64;
    const int nch = wave & 3, cohalf = wave >> 2;

    constexpr float kLog2e = 1.44269504f;

    // stage x tile [256 ci][64 n]
    {
        const int r4i = lane >> 4, c16 = lane & 15;
        const float* xg = x + (size_t)b * kCHW + (size_t)r4i * kHW + n0 + c16 * 4;
#pragma unroll
        for (int j = 0; j < 8; ++j) {
            const int cibase = (wave * 8 + j) * 4;
            __builtin_amdgcn_global_load_lds(
                (const __attribute__((address_space(1))) void*)(xg + (size_t)cibase * kHW),
                (__attribute__((address_space(3))) void*)&xs[cibase][0], 16, 0, 0);
        }
    }
    if (t < 320) bLDS[t] = (t < 32) ? fb[t]
                         : (t < 64) ? gb[t - 32] * kLog2e
                         : hb[t - 64];
    __syncthreads();

    // B-frags (x) hi/lo for 8 ci-slices; lane = col n
    const int n = nch * 16 + l15;
    bf16x8 bh[8], bl[8];
#pragma unroll
    for (int s = 0; s < 8; ++s) {
        union { u16 a[8]; bf16x8 v; } H, L;
#pragma unroll
        for (int j = 0; j < 8; ++j) {
            const float v = xs[s * 32 + quad * 8 + j][n];
            const u16 h = f2bf(v);
            H.a[j] = h; L.a[j] = f2bf(v - bf2f(h));
        }
        bh[s] = H.v; bl[s] = L.v;
    }

    // A-frag lane base into packed layout
    const u16* whp = wh + l15 * 32 + quad * 8;
    const u16* wlp = wl + l15 * 32 + quad * 8;

    f32x4 acc[10] = {};
#pragma unroll
    for (int c = 0; c < 10; ++c) {
        const size_t base = (size_t)(cohalf * 10 + c) * 4096;
#pragma unroll
        for (int s = 0; s < 8; ++s) {
            const bf16x8 ah = *(const bf16x8*)(whp + base + s * 512);
            const bf16x8 al = *(const bf16x8*)(wlp + base + s * 512);
            acc[c] = __builtin_amdgcn_mfma_f32_16x16x32_bf16(ah, bh[s], acc[c], 0, 0, 0);
            acc[c] = __builtin_amdgcn_mfma_f32_16x16x32_bf16(ah, bl[s], acc[c], 0, 0, 0);
            acc[c] = __builtin_amdgcn_mfma_f32_16x16x32_bf16(al, bh[s], acc[c], 0, 0, 0);
        }
    }

    const float s0 = sig[0], s1 = sig[1] * kLog2e, s2 = sig[2];
#pragma unroll
    for (int c = 0; c < 10; ++c) {
        const int cog0 = (cohalf * 10 + c) * 16;
        const float inv = (cog0 < 32) ? s0 : (cog0 < 64) ? s1 : s2;
        if (cog0 < 64) {
            // K/Q: r=0..3 -> consecutive d; pack into uint2 hi + uint2 lo
            u16 hi[4], lo[4];
#pragma unroll
            for (int r = 0; r < 4; ++r) {
                const float v = acc[c][r] * inv + bLDS[cog0 + quad * 4 + r];
                hi[r] = f2bf(v);
                lo[r] = f2bf(v - bf2f(hi[r]));
            }
            u16* H = (cog0 < 32) ? Kc : Qc;
            const int dbase = (cog0 & 31) + quad * 4;
            const size_t off = (size_t)(b * kHW + n0 + n) * 64;
            const unsigned h01 = (unsigned)hi[0] | ((unsigned)hi[1] << 16);
            const unsigned h23 = (unsigned)hi[2] | ((unsigned)hi[3] << 16);
            const unsigned l01 = (unsigned)lo[0] | ((unsigned)lo[1] << 16);
            const unsigned l23 = (unsigned)lo[2] | ((unsigned)lo[3] << 16);
            *(uint2*)(H + off + dbase)      = make_uint2(h01, h23);
            *(uint2*)(H + off + 32 + dbase) = make_uint2(l01, l23);
        } else {
#pragma unroll
            for (int r = 0; r < 4; ++r) {
                const int co = cog0 + quad * 4 + r;
                const float v = acc[c][r] * inv + bLDS[co];
                Vb[((size_t)b * kC + (co - 64)) * kHW + n0 + n] = f2bf(v);
            }
        }
    }
}

// ---------------------------------------------------------------------------
// Kernel 3: flash attention (v13 verified, unchanged).  grid 512
// (XCD-swizzled; id>>8 = key-half), 512 thr (8 waves).  Single barrier per
// m-tile; Qt gld_lds staging prefetched one tile ahead; V single-buffered;
// setprio(1) around MFMA clusters; max-free softmax (exp2, log2e folded
// into Q projection).
// ---------------------------------------------------------------------------
__global__ __launch_bounds__(512, 4) void k_attn(
    const u16* __restrict__ Kc, const u16* __restrict__ Qc,
    const u16* __restrict__ Vb,
    u16* __restrict__ Op, float* __restrict__ Sl)
{
    __shared__ __align__(16) u16 Qt[2][4096];   // 16 KB
    __shared__ __align__(16) u16 Pt[2][4096];   // 16 KB
    __shared__ float lsum[8][16];

    const int t = threadIdx.x;
    const int wave = t >> 6, lane = t & 63;
    const int quad = lane >> 4, l15 = lane & 15;
    const int sg = wave >> 1, half = wave & 1;

    const int id = blockIdx.x;
    const int xcd = id & 7;
    const int b = xcd >> 1;
    const int nb0 = ((xcd & 1) * 32 + ((id >> 3) & 31)) * 64;
    const int mh = id >> 8;                    // key-half
    const int mt0 = mh * 32, mt1 = mt0 + 32;

    const u16* Kb  = Kc + (size_t)b * kHW * 64;
    const u16* Qb  = Qc + (size_t)b * kHW * 64;
    const u16* Vbb = Vb + (size_t)b * kC * kHW;

    const size_t krow = (size_t)(nb0 + sg * 16 + l15) * 64 + (size_t)quad * 8;
    const bf16x8 kh = *(const bf16x8*)(Kb + krow);
    const bf16x8 kl = *(const bf16x8*)(Kb + krow + 32);

    const u16* vrow[2];
#pragma unroll
    for (int ct = 0; ct < 2; ++ct)
        vrow[ct] = Vbb + (size_t)(wave * 32 + ct * 16 + l15) * kHW + quad * 8;

    const int qs_row = lane >> 3, qs_ch = lane & 7;
    const int rloc = wave * 8 + qs_row;
    const int qswz = (qs_ch ^ (rloc & 7)) << 3;

    f32x4 O[8] = {};
    float lrow = 0.f;
    bf16x8 vc[4];

    // ---- prologue: stage Qt[0] (tile mt0), barrier ----
    __builtin_amdgcn_global_load_lds(
        (const __attribute__((address_space(1))) void*)
            (Qb + (size_t)(mt0 * 64 + rloc) * 64 + qswz),
        (__attribute__((address_space(3))) void*)&Qt[0][wave * 512], 16, 0, 0);
    __syncthreads();

    for (int mt = mt0; mt < mt1; ++mt) {
        const int cur = mt & 1;
        const int m0 = mt * 64;   // key units

        // ---- issue Qt load for tile mt+1 (consumed after next barrier) ----
        if (mt < mt1 - 1) {
            __builtin_amdgcn_global_load_lds(
                (const __attribute__((address_space(1))) void*)
                    (Qb + (size_t)(m0 + 64 + rloc) * 64 + qswz),
                (__attribute__((address_space(3))) void*)&Qt[cur ^ 1][wave * 512], 16, 0, 0);
        }
        // ---- V for the CURRENT tile (consumed in PV after the barrier) ----
#pragma unroll
        for (int ct = 0; ct < 2; ++ct)
#pragma unroll
            for (int ks = 0; ks < 2; ++ks)
                vc[ct * 2 + ks] = *(const bf16x8*)(vrow[ct] + m0 + ks * 32);

        // ---- scores for this wave's m-half (Qt[cur] ready since c_{i-1}) ----
        f32x4 s[2];
        __builtin_amdgcn_s_setprio(1);
#pragma unroll
        for (int mi2 = 0; mi2 < 2; ++mi2) {
            const int mi = half * 2 + mi2;
            const int rbase = (mi * 16 + l15) * 64;
            const bf16x8 qhv = *(const bf16x8*)&Qt[cur][rbase + ((quad       ^ (l15 & 7)) << 3)];
            const bf16x8 qlv = *(const bf16x8*)&Qt[cur][rbase + (((quad + 4) ^ (l15 & 7)) << 3)];
            f32x4 a = { 0.f, 0.f, 0.f, 0.f };
            a = __builtin_amdgcn_mfma_f32_16x16x32_bf16(qhv, kl, a, 0, 0, 0);
            a = __builtin_amdgcn_mfma_f32_16x16x32_bf16(qlv, kh, a, 0, 0, 0);
            a = __builtin_amdgcn_mfma_f32_16x16x32_bf16(qhv, kh, a, 0, 0, 0);
            s[mi2] = a;
        }
        __builtin_amdgcn_s_setprio(0);

        // ---- exp2 + l accumulate + pack P (truncated bf16) -> Pt[cur] ----
        {
            const int prow = sg * 16 + l15;
#pragma unroll
            for (int mi2 = 0; mi2 < 2; ++mi2) {
                const float p0 = EXP2(s[mi2][0]);
                const float p1 = EXP2(s[mi2][1]);
                const float p2 = EXP2(s[mi2][2]);
                const float p3 = EXP2(s[mi2][3]);
                lrow += (p0 + p1) + (p2 + p3);
                const unsigned d0 = __builtin_amdgcn_perm(
                    __float_as_uint(p1), __float_as_uint(p0), 0x07060302u);
                const unsigned d1 = __builtin_amdgcn_perm(
                    __float_as_uint(p3), __float_as_uint(p2), 0x07060302u);
                const int mi = half * 2 + mi2;
                const int chunk = 2 * mi + (quad >> 1);
                const int off = prow * 64 + ((chunk ^ (l15 & 7)) << 3) + (quad & 1) * 4;
                *(uint2*)(Pt[cur] + off) = make_uint2(d0, d1);
            }
        }

        __syncthreads();   // single barrier: Pt[cur] ready; Qt[cur^1] staged

        // ---- PV ----
        __builtin_amdgcn_s_setprio(1);
#pragma unroll
        for (int ks = 0; ks < 2; ++ks) {
#pragma unroll
            for (int rg = 0; rg < 4; ++rg) {
                const bf16x8 pa = *(const bf16x8*)&Pt[cur][(rg * 16 + l15) * 64
                                     + (((ks * 4 + quad) ^ (l15 & 7)) << 3)];
#pragma unroll
                for (int ct = 0; ct < 2; ++ct)
                    O[rg * 2 + ct] = __builtin_amdgcn_mfma_f32_16x16x32_bf16(
                        pa, vc[ct * 2 + ks], O[rg * 2 + ct], 0, 0, 0);
            }
        }
        __builtin_amdgcn_s_setprio(0);
    }

    // ---- epilogue: reduce l once, write bf16 partial O + l ----
    lrow += __shfl_xor(lrow, 16);
    lrow += __shfl_xor(lrow, 32);
    if (lane < 16) lsum[wave][l15] = lrow;
    __syncthreads();
    if (half == 0 && lane < 16)
        Sl[(size_t)(mh * 4 + b) * kHW + nb0 + sg * 16 + l15]
            = lsum[wave][l15] + lsum[wave ^ 1][l15];

    u16* Opb = Op + (size_t)(mh * 4 + b) * kHW * 256;
#pragma unroll
    for (int rg = 0; rg < 4; ++rg) {
#pragma unroll
        for (int ct = 0; ct < 2; ++ct) {
#pragma unroll
            for (int r = 0; r < 4; ++r) {
                const int nn = nb0 + rg * 16 + quad * 4 + r;
                const int c = wave * 32 + ct * 16 + l15;
                Opb[(size_t)nn * 256 + c] = f2bf(O[rg * 2 + ct][r]);
            }
        }
    }
}

// ---------------------------------------------------------------------------
// Kernel 4: merge the two key-halves + epilogue.  grid 2048 x 256 thr,
// 8 channels per thread, fully coalesced.  Max-free partials: plain sums.
// ---------------------------------------------------------------------------
__global__ __launch_bounds__(256) void k_merge(
    const float* __restrict__ x, const float* __restrict__ gamma,
    const u16* __restrict__ Op, const float* __restrict__ Sl,
    float* __restrict__ out)
{
    const int tid = blockIdx.x * 256 + threadIdx.x;
    const int cg = tid & 31;
    const int n  = (tid >> 5) & 4095;
    const int b  = tid >> 17;
    const int c0 = cg * 8;

    const float la = Sl[(size_t)b * kHW + n];
    const float lb = Sl[(size_t)(4 + b) * kHW + n];
    const float invL = 1.f / (la + lb);
    const float g = gamma[0];

    const size_t base = ((size_t)b * kHW + n) * 256 + c0;
    const uint4 A = *(const uint4*)(Op + base);
    const uint4 B = *(const uint4*)(Op + base + (size_t)4 * kHW * 256);
    const float4 x0 = *(const float4*)(x + base);
    const float4 x1 = *(const float4*)(x + base + 4);

    float o[8];
    const unsigned aw[4] = { A.x, A.y, A.z, A.w };
    const unsigned bw[4] = { B.x, B.y, B.z, B.w };
#pragma unroll
    for (int j = 0; j < 8; ++j) {
        const float va = bf2f((u16)(aw[j >> 1] >> ((j & 1) * 16)));
        const float vb = bf2f((u16)(bw[j >> 1] >> ((j & 1) * 16)));
        o[j] = (va + vb) * invL;
    }
    float4 r0, r1;
    r0.x = g * o[0] + x0.x; r0.y = g * o[1] + x0.y;
    r0.z = g * o[2] + x0.z; r0.w = g * o[3] + x0.w;
    r1.x = g * o[4] + x1.x; r1.y = g * o[5] + x1.y;
    r1.z = g * o[6] + x1.z; r1.w = g * o[7] + x1.w;
    *(float4*)(out + base)     = r0;
    *(float4*)(out + base + 4) = r1;
}

// ---------------------------------------------------------------------------
extern "C" void kernel_launch(void* const* d_in, const int* in_sizes, int n_in,
                              void* d_out, int out_size, void* d_ws, size_t ws_size,
                              hipStream_t stream)
{
    const float* x     = (const float*)d_in[0];
    const float* fw    = (const float*)d_in[1];
    const float* fb    = (const float*)d_in[2];
    const float* fu    = (const float*)d_in[3];
    const float* gw    = (const float*)d_in[4];
    const float* gb    = (const float*)d_in[5];
    const float* gu    = (const float*)d_in[6];
    const float* hww   = (const float*)d_in[7];
    const float* hb    = (const float*)d_in[8];
    const float* hu    = (const float*)d_in[9];
    const float* gamma = (const float*)d_in[10];
    float* out = (float*)d_out;

    char* ws = (char*)d_ws;
    float* sig = (float*)ws;                        // 3 floats
    u16* wh = (u16*)(ws + 1024);                    // packed 320x256 bf16 hi
    u16* wl = wh + 320 * 256;                       // packed lo
    u16* Kc = (u16*)(ws + (1u << 20));              // 2 MB
    u16* Qc = (u16*)(ws + (3u << 20));              // 2 MB
    u16* Vb = (u16*)(ws + (5u << 20));              // 8 MB
    u16* Op = (u16*)(ws + (16u << 20));             // 16 MB: [2][4][4096][256] bf16
    float* Sl = (float*)(ws + (32u << 20));         // 128 KB: [2][4][4096] float

    k_prep<<<dim3(83), dim3(1024), 0, stream>>>(fw, fu, gw, gu, hww, hu, sig, wh, wl);
    k_proj<<<dim3(64, 4), dim3(512), 0, stream>>>(x, wh, wl, fb, gb, hb, sig,
                                                  Kc, Qc, Vb);
    k_attn<<<dim3(512), dim3(512), 0, stream>>>(Kc, Qc, Vb, Op, Sl);
    k_merge<<<dim3(2048), dim3(256), 0, stream>>>(x, gamma, Op, Sl, out);
}